// Round 2
// baseline (849.928 us; speedup 1.0000x reference)
//
#include <hip/hip_runtime.h>
#include <math.h>

#define BATCH 4096
#define NSIG  16384
#define MREF  12
#define KBIN  2048

constexpr float SIM_EPS = 1e-4f;
constexpr int CH = 64;              // n2 columns per chunk
constexpr int NCHUNK = 128 / CH;    // 2

// ---- pre-kernel: msn[m] = sum_k model_spectra[m][k]^2 ----
__global__ __launch_bounds__(256) void msnorm_kernel(const float* __restrict__ ms,
                                                     float* __restrict__ msn) {
  int m = blockIdx.x, t = threadIdx.x;
  float p = 0.f;
  for (int i = t; i < KBIN; i += 256) { float v = ms[m * KBIN + i]; p += v * v; }
  #pragma unroll
  for (int o = 32; o; o >>= 1) p += __shfl_xor(p, o, 64);
  __shared__ float r[4];
  if ((t & 63) == 0) r[t >> 6] = p;
  __syncthreads();
  if (t == 0) msn[m] = r[0] + r[1] + r[2] + r[3];
}

// ---- main: per-batch 2048-bin DFT (two-stage CT) + similarity reduction ----
__global__ __launch_bounds__(256) void consonance_kernel(
    const float* __restrict__ Y, const float* __restrict__ ms,
    const float* __restrict__ diss, const float* __restrict__ msn,
    float* __restrict__ out) {
  __shared__ float  Ys[128][CH];        // 32 KB: Y chunk, [n1][n2c]
  __shared__ float  Trr[65][CH + 1];    // stage-1 out (real), rows k1'=0..64 (conj-sym)
  __shared__ float  Tii[65][CH + 1];    // stage-1 out (imag); stride 65 words == 1 mod 32
  __shared__ float2 tabA[128];          // e^{-2pi i j/128}
  __shared__ float2 tabB[128];          // e^{-2pi i j/16384}
  __shared__ float  red[4][13];

  const int t = threadIdx.x;
  const int b = blockIdx.x;

  if (t < 128) {
    float s, c;
    sincosf(6.2831853071795864769f * (float)t / 128.0f, &s, &c);
    tabA[t] = make_float2(c, -s);
    sincosf(6.2831853071795864769f * (float)t / 16384.0f, &s, &c);
    tabB[t] = make_float2(c, -s);
  }

  // stage-2 ownership: k = k1 + 128*(k2b+j), j<8
  const int k1  = t & 127;
  const int k2b = (t >> 7) * 8;
  int k1s; float sgn;
  if (k1 <= 64) { k1s = k1; sgn = 1.f; } else { k1s = 128 - k1; sgn = -1.f; }

  // stage-1 ownership: rows g*4+j (j<4), cols n2g*4..+3
  const int n2g = t & 15;
  const int g   = t >> 4;

  float xre[8], xim[8];
  #pragma unroll
  for (int j = 0; j < 8; ++j) { xre[j] = 0.f; xim[j] = 0.f; }

  __syncthreads();  // tables ready

  for (int ch = 0; ch < NCHUNK; ++ch) {
    // ---- load Y chunk: Ys[n1][c] = Y[b, n1*128 + ch*64 + c] ----
    const float* ybase = Y + (size_t)b * NSIG + ch * CH;
    #pragma unroll
    for (int q = 0; q < 8; ++q) {
      int i = q * 256 + t;            // [0, 2048) float4-index
      int n1 = i >> 4, c4 = i & 15;
      float4 v = *(const float4*)(ybase + n1 * 128 + c4 * 4);
      *(float4*)&Ys[n1][c4 * 4] = v;
    }
    __syncthreads();

    // ---- stage 1: T[k1', n2] = sum_n1 Y[n1*128+n2] * e^{-2pi i k1' n1/128} ----
    float ar[4][4], ai[4][4];
    #pragma unroll
    for (int j = 0; j < 4; ++j)
      #pragma unroll
      for (int c = 0; c < 4; ++c) { ar[j][c] = 0.f; ai[j][c] = 0.f; }
    float er[4] = {0.f, 0.f, 0.f, 0.f};          // row k1'=64 (imag = 0)
    for (int n1 = 0; n1 < 128; ++n1) {
      float4 y = *(const float4*)&Ys[n1][n2g * 4];
      float yy[4] = {y.x, y.y, y.z, y.w};
      #pragma unroll
      for (int j = 0; j < 4; ++j) {
        float2 w = tabA[((g * 4 + j) * n1) & 127];
        #pragma unroll
        for (int c = 0; c < 4; ++c) {
          ar[j][c] = fmaf(yy[c], w.x, ar[j][c]);
          ai[j][c] = fmaf(yy[c], w.y, ai[j][c]);
        }
      }
      if (g == 0) {
        float sg = (n1 & 1) ? -1.f : 1.f;
        #pragma unroll
        for (int c = 0; c < 4; ++c) er[c] = fmaf(yy[c], sg, er[c]);
      }
    }
    #pragma unroll
    for (int j = 0; j < 4; ++j)
      #pragma unroll
      for (int c = 0; c < 4; ++c) {
        Trr[g * 4 + j][n2g * 4 + c] = ar[j][c];
        Tii[g * 4 + j][n2g * 4 + c] = ai[j][c];
      }
    if (g == 0) {
      #pragma unroll
      for (int c = 0; c < 4; ++c) {
        Trr[64][n2g * 4 + c] = er[c];
        Tii[64][n2g * 4 + c] = 0.f;
      }
    }
    __syncthreads();

    // ---- stage 2: X[k1+128k2] += T[k1,n2] e^{-2pi i k1 n2/16384} e^{-2pi i k2 n2/128} ----
    for (int c = 0; c < CH; ++c) {
      int n2 = ch * CH + c;
      float tr = Trr[k1s][c];
      float ti = sgn * Tii[k1s][c];              // conj for k1 > 64
      int idx = k1 * n2;                         // < 16384
      float2 wa = tabA[idx >> 7];
      float2 wb = tabB[idx & 127];
      float w1r = wa.x * wb.x - wa.y * wb.y;
      float w1i = wa.x * wb.y + wa.y * wb.x;
      float ur = tr * w1r - ti * w1i;
      float ui = tr * w1i + ti * w1r;
      #pragma unroll
      for (int j = 0; j < 8; ++j) {
        float2 w2 = tabA[((k2b + j) * n2) & 127];
        xre[j] = fmaf(ur, w2.x, fmaf(-ui, w2.y, xre[j]));
        xim[j] = fmaf(ur, w2.y, fmaf( ui, w2.x, xim[j]));
      }
    }
    __syncthreads();
  }

  // ---- magnitude + fused similarity reduction ----
  const float scale = 2.0f / (float)NSIG;
  float yf[8], S = 0.f;
  #pragma unroll
  for (int j = 0; j < 8; ++j) {
    yf[j] = scale * sqrtf(xre[j] * xre[j] + xim[j] * xim[j]);
    S += yf[j] * yf[j];
  }
  float dot[MREF];
  #pragma unroll
  for (int m = 0; m < MREF; ++m) dot[m] = 0.f;
  #pragma unroll
  for (int m = 0; m < MREF; ++m) {
    const float* msrow = ms + m * KBIN + k1;
    #pragma unroll
    for (int j = 0; j < 8; ++j)
      dot[m] = fmaf(yf[j], msrow[(k2b + j) * 128], dot[m]);
  }

  #pragma unroll
  for (int o = 32; o; o >>= 1) {
    S += __shfl_xor(S, o, 64);
    #pragma unroll
    for (int m = 0; m < MREF; ++m) dot[m] += __shfl_xor(dot[m], o, 64);
  }
  int wave = t >> 6, lane = t & 63;
  if (lane == 0) {
    red[wave][0] = S;
    #pragma unroll
    for (int m = 0; m < MREF; ++m) red[wave][1 + m] = dot[m];
  }
  __syncthreads();
  if (t == 0) {
    float St = red[0][0] + red[1][0] + red[2][0] + red[3][0];
    float ssum = 0.f, wsum = 0.f;
    for (int m = 0; m < MREF; ++m) {
      float dm = red[0][1 + m] + red[1][1 + m] + red[2][1 + m] + red[3][1 + m];
      float d2 = St + msn[m] - 2.f * dm;
      float dist = sqrtf(fmaxf(d2, 0.f));
      float sim = 1.f / (dist + SIM_EPS);
      ssum += sim;
      wsum += sim * (1.f - diss[m]);
    }
    out[b] = wsum / ssum;
  }
}

extern "C" void kernel_launch(void* const* d_in, const int* in_sizes, int n_in,
                              void* d_out, int out_size, void* d_ws, size_t ws_size,
                              hipStream_t stream) {
  const float* Y    = (const float*)d_in[0];
  const float* ms   = (const float*)d_in[1];
  const float* diss = (const float*)d_in[2];
  float* msn = (float*)d_ws;
  float* outp = (float*)d_out;
  msnorm_kernel<<<MREF, 256, 0, stream>>>(ms, msn);
  consonance_kernel<<<BATCH, 256, 0, stream>>>(Y, ms, diss, msn, outp);
}

// Round 5
// 406.907 us; speedup vs baseline: 2.0888x; 2.0888x over previous
//
#include <hip/hip_runtime.h>
#include <hip/hip_bf16.h>
#include <math.h>

#define BATCH 4096
#define NSIG  16384
#define MREF  12
#define KBIN  2048

constexpr float SIM_EPS = 1e-4f;

typedef __attribute__((ext_vector_type(8))) short bfrag;   // 8 bf16 (4 VGPR)
typedef __attribute__((ext_vector_type(4))) float f32x4;
typedef __attribute__((ext_vector_type(4))) int   i32x4;

__device__ inline unsigned short f2bf(float x) {
  unsigned u = __builtin_bit_cast(unsigned, x);
  u += 0x7fffu + ((u >> 16) & 1u);      // round-to-nearest-even
  return (unsigned short)(u >> 16);
}
__device__ inline unsigned pkbf(float lo, float hi) {
  return (unsigned)f2bf(lo) | ((unsigned)f2bf(hi) << 16);   // low 16 = lo
}
__device__ inline f32x4 mfma16(bfrag a, bfrag b, f32x4 c) {
  return __builtin_amdgcn_mfma_f32_16x16x32_bf16(a, b, c, 0, 0, 0);
}
__device__ inline bfrag mk_frag(unsigned w0, unsigned w1, unsigned w2, unsigned w3) {
  i32x4 v = {(int)w0, (int)w1, (int)w2, (int)w3};
  return __builtin_bit_cast(bfrag, v);
}

// ---- pre-kernel: msn[m] = sum_k model_spectra[m][k]^2 ----
__global__ __launch_bounds__(256) void msnorm_kernel(const float* __restrict__ ms,
                                                     float* __restrict__ msn) {
  int m = blockIdx.x, t = threadIdx.x;
  float p = 0.f;
  for (int i = t; i < KBIN; i += 256) { float v = ms[m * KBIN + i]; p += v * v; }
  #pragma unroll
  for (int o = 32; o; o >>= 1) p += __shfl_xor(p, o, 64);
  __shared__ float r[4];
  if ((t & 63) == 0) r[t >> 6] = p;
  __syncthreads();
  if (t == 0) msn[m] = r[0] + r[1] + r[2] + r[3];
}

// ---- main: per-batch 2048-bin DFT via two-stage CT, both stages MFMA ----
// N = 128*n1 + n2 ; k = k1 + 128*k2, k1 in [0,128), k2 in [0,16)
// stage1: T[k1,n2] = sum_n1 Y[128 n1 + n2] W[k1,n1],  W = e^{-2pi i k1 n1/128}
// U[k1,n2] = T * e^{-2pi i k1 n2 / 16384}
// stage2: X[k1,k2] = sum_n2 U[k1,n2] e^{-2pi i k2 n2/128}  (complex via real-pack GEMM)
__global__ __launch_bounds__(256, 2) void consonance_kernel(
    const float* __restrict__ Y, const float* __restrict__ ms,
    const float* __restrict__ diss, const float* __restrict__ msn,
    float* __restrict__ out) {
  __shared__ __align__(16) unsigned short Ysb[128 * 128]; // bf16 [n2][n1], 16B-block XOR swizzle
  __shared__ __align__(16) unsigned Ua[4 * 32 * 32];      // per-wave packed U (bf16 re|im), swizzled
  __shared__ float2 tabA2[128];   // e^{-2pi i j/128}  = (cos, -sin)
  __shared__ float2 tabB[128];    // e^{-2pi i j/16384}
  __shared__ float red[4][13];

  const int t = threadIdx.x;
  const int b = blockIdx.x;
  const int lane = t & 63;
  const int w = t >> 6;           // wave 0..3, owns k1 in [32w, 32w+32)
  const int g = lane >> 4;        // 0..3
  const int c = lane & 15;        // 0..15

  if (t < 128) {
    float s, cf;
    sincosf(6.2831853071795864769f * (float)t / 128.0f, &s, &cf);
    tabA2[t] = make_float2(cf, -s);
    sincosf(6.2831853071795864769f * (float)t / 16384.0f, &s, &cf);
    tabB[t] = make_float2(cf, -s);
  }

  // ---- load Y row -> bf16 transposed swizzled LDS: Ysb[n2][n1] ----
  {
    const int c0 = (t & 31) << 2;         // n2 base (4 cols)
    const int h  = t >> 5;                // 0..7 -> n1 range [16h,16h+16)
    const float* yrow = Y + (size_t)b * NSIG + c0;
    float4 v[16];
    #pragma unroll
    for (int r = 0; r < 16; ++r)
      v[r] = *(const float4*)(yrow + 128 * (16 * h + r));
    #pragma unroll
    for (int u = 0; u < 2; ++u) {
      #pragma unroll
      for (int cc = 0; cc < 4; ++cc) {
        const int n2 = c0 + cc;
        unsigned p0 = pkbf((&v[8*u+0].x)[cc], (&v[8*u+1].x)[cc]);
        unsigned p1 = pkbf((&v[8*u+2].x)[cc], (&v[8*u+3].x)[cc]);
        unsigned p2 = pkbf((&v[8*u+4].x)[cc], (&v[8*u+5].x)[cc]);
        unsigned p3 = pkbf((&v[8*u+6].x)[cc], (&v[8*u+7].x)[cc]);
        const int blk = (2 * h + u) ^ (n2 & 7);
        *(i32x4*)((char*)Ysb + n2 * 256 + (blk << 4)) =
            (i32x4){(int)p0, (int)p1, (int)p2, (int)p3};
      }
    }
  }
  __syncthreads();   // tables + Ysb ready; ONLY barrier before reduction

  // ---- W fragments (stage-1 A operand), registers, bf16 ----
  // A-frag: lane holds A[row = c][k = 8g + j + 32ks], row -> k1 = 32w+16mt+c
  bfrag Wr[2][4], Wi[2][4];
  #pragma unroll
  for (int mt = 0; mt < 2; ++mt) {
    const int k1 = 32 * w + 16 * mt + c;
    const float2 rw = tabA2[k1 & 127];
    #pragma unroll
    for (int ks = 0; ks < 4; ++ks) {
      const int n10 = 32 * ks + 8 * g;
      float2 e = tabA2[(k1 * n10) & 127];
      unsigned pr[4], pi[4];
      #pragma unroll
      for (int jp = 0; jp < 4; ++jp) {
        const float e0x = e.x, e0y = e.y;
        float nx = e.x * rw.x - e.y * rw.y;
        float ny = e.x * rw.y + e.y * rw.x;
        e.x = nx; e.y = ny;                       // j = 2jp+1
        pr[jp] = pkbf(e0x, e.x);
        pi[jp] = pkbf(e0y, e.y);
        nx = e.x * rw.x - e.y * rw.y;
        ny = e.x * rw.y + e.y * rw.x;
        e.x = nx; e.y = ny;                       // j = 2jp+2
      }
      Wr[mt][ks] = mk_frag(pr[0], pr[1], pr[2], pr[3]);
      Wi[mt][ks] = mk_frag(pi[0], pi[1], pi[2], pi[3]);
    }
  }
  const float2 rotB = tabA2[c];   // e^{-2pi i k2/128}, k2 = c

  f32x4 aXr[2] = {{0.f,0.f,0.f,0.f},{0.f,0.f,0.f,0.f}};   // [mt] cols = Xr(k2)
  f32x4 aXi[2] = {{0.f,0.f,0.f,0.f},{0.f,0.f,0.f,0.f}};   // [mt] cols = Xi(k2)
  unsigned* uw = Ua + (w << 10);  // 1024 words per wave (32 rows x 32)

  #pragma unroll 1
  for (int ch = 0; ch < 4; ++ch) {
    // ---- stage-1 B-frags from Ysb: B[k=n1][col=n2-local] ----
    bfrag bfr[2][4];
    #pragma unroll
    for (int nt = 0; nt < 2; ++nt) {
      const int n2 = 32 * ch + 16 * nt + c;
      #pragma unroll
      for (int ks = 0; ks < 4; ++ks) {
        const int blk = (4 * ks + g) ^ (n2 & 7);
        bfr[nt][ks] = *(const bfrag*)((const char*)Ysb + n2 * 256 + (blk << 4));
      }
    }
    // ---- stage-1 MFMA ----
    f32x4 aTr[2][2] = {{{0.f,0.f,0.f,0.f},{0.f,0.f,0.f,0.f}},
                       {{0.f,0.f,0.f,0.f},{0.f,0.f,0.f,0.f}}};
    f32x4 aTi[2][2] = {{{0.f,0.f,0.f,0.f},{0.f,0.f,0.f,0.f}},
                       {{0.f,0.f,0.f,0.f},{0.f,0.f,0.f,0.f}}};
    #pragma unroll
    for (int mt = 0; mt < 2; ++mt)
      #pragma unroll
      for (int nt = 0; nt < 2; ++nt)
        #pragma unroll
        for (int ks = 0; ks < 4; ++ks) {
          aTr[mt][nt] = mfma16(Wr[mt][ks], bfr[nt][ks], aTr[mt][nt]);
          aTi[mt][nt] = mfma16(Wi[mt][ks], bfr[nt][ks], aTi[mt][nt]);
        }
    // ---- U = T * e^{-2pi i k1 n2/16384}, pack bf16, write per-wave LDS ----
    // C/D layout: row = 4g+q (+16mt), col = c (+16nt)
    #pragma unroll
    for (int nt = 0; nt < 2; ++nt) {
      const int n2 = 32 * ch + 16 * nt + c;
      const float2 stp = tabB[n2];              // rotation for k1 -> k1+1
      #pragma unroll
      for (int mt = 0; mt < 2; ++mt) {
        const int k10 = 32 * w + 16 * mt + 4 * g;
        const int a0 = (k10 * n2) & 16383;
        const float2 ea = tabA2[a0 >> 7], eb = tabB[a0 & 127];
        float twr = ea.x * eb.x - ea.y * eb.y;
        float twi = ea.x * eb.y + ea.y * eb.x;
        #pragma unroll
        for (int q = 0; q < 4; ++q) {
          const float tr = aTr[mt][nt][q], ti = aTi[mt][nt][q];
          const float ur = tr * twr - ti * twi;
          const float ui = tr * twi + ti * twr;
          const int rl = 16 * mt + 4 * g + q;
          const int tt = 16 * nt + c;
          uw[rl * 32 + (tt ^ ((rl & 7) << 2))] = pkbf(ur, ui);
          const float nr = twr * stp.x - twi * stp.y;
          const float ni = twr * stp.y + twi * stp.x;
          twr = nr; twi = ni;
        }
      }
    }
    // ---- stage-2 B-frags (V twiddles), rebuilt per chunk in regs ----
    // B_pack[2t][k2]=Vr, B_pack[2t][16+k2]=Vi, B_pack[2t+1][k2]=-Vi, B_pack[2t+1][16+k2]=Vr
    // tabA2[(k2*n2)&127] = (Vr, Vi) directly.
    bfrag B2[2][2];   // [ntile(Xr/Xi)][s]
    #pragma unroll
    for (int s = 0; s < 2; ++s) {
      const int t0 = 16 * s + 4 * g;
      float2 e = tabA2[(c * (32 * ch + t0)) & 127];
      unsigned p0[4], p1[4];
      #pragma unroll
      for (int i = 0; i < 4; ++i) {
        p0[i] = pkbf(e.x, -e.y);                // (Vr, -Vi)
        p1[i] = pkbf(e.y,  e.x);                // (Vi,  Vr)
        const float nx = e.x * rotB.x - e.y * rotB.y;
        const float ny = e.x * rotB.y + e.y * rotB.x;
        e.x = nx; e.y = ny;
      }
      B2[0][s] = mk_frag(p0[0], p0[1], p0[2], p0[3]);
      B2[1][s] = mk_frag(p1[0], p1[1], p1[2], p1[3]);
    }
    // ---- stage-2 MFMA: A from own-wave LDS (no barrier needed) ----
    #pragma unroll
    for (int mt = 0; mt < 2; ++mt) {
      const int rl = 16 * mt + c;
      #pragma unroll
      for (int s = 0; s < 2; ++s) {
        const int t4 = (16 * s + 4 * g) ^ ((rl & 7) << 2);
        bfrag af = *(const bfrag*)((const char*)uw + rl * 128 + (t4 << 2));
        aXr[mt] = mfma16(af, B2[0][s], aXr[mt]);
        aXi[mt] = mfma16(af, B2[1][s], aXi[mt]);
      }
    }
  }

  // ---- magnitude + fused similarity reduction ----
  // lane holds X(k1 = 32w+16mt+4g+q, k2 = c) -> k = k1 + 128*k2
  const float scale = 2.0f / (float)NSIG;
  float S = 0.f;
  float dot[MREF];
  #pragma unroll
  for (int m = 0; m < MREF; ++m) dot[m] = 0.f;
  #pragma unroll
  for (int mt = 0; mt < 2; ++mt) {
    #pragma unroll
    for (int q = 0; q < 4; ++q) {
      const float xr = aXr[mt][q], xi = aXi[mt][q];
      const float yf = scale * sqrtf(xr * xr + xi * xi);
      S += yf * yf;
      const int k = 32 * w + 16 * mt + 4 * g + q + 128 * c;
      #pragma unroll
      for (int m = 0; m < MREF; ++m)
        dot[m] = fmaf(yf, ms[m * KBIN + k], dot[m]);
    }
  }
  #pragma unroll
  for (int o = 32; o; o >>= 1) {
    S += __shfl_xor(S, o, 64);
    #pragma unroll
    for (int m = 0; m < MREF; ++m) dot[m] += __shfl_xor(dot[m], o, 64);
  }
  if (lane == 0) {
    red[w][0] = S;
    #pragma unroll
    for (int m = 0; m < MREF; ++m) red[w][1 + m] = dot[m];
  }
  __syncthreads();
  if (t == 0) {
    const float St = red[0][0] + red[1][0] + red[2][0] + red[3][0];
    float ssum = 0.f, wsum = 0.f;
    for (int m = 0; m < MREF; ++m) {
      const float dm = red[0][1 + m] + red[1][1 + m] + red[2][1 + m] + red[3][1 + m];
      const float d2 = St + msn[m] - 2.f * dm;
      const float dist = sqrtf(fmaxf(d2, 0.f));
      const float sim = 1.f / (dist + SIM_EPS);
      ssum += sim;
      wsum += sim * (1.f - diss[m]);
    }
    out[b] = wsum / ssum;
  }
}

extern "C" void kernel_launch(void* const* d_in, const int* in_sizes, int n_in,
                              void* d_out, int out_size, void* d_ws, size_t ws_size,
                              hipStream_t stream) {
  const float* Y    = (const float*)d_in[0];
  const float* ms   = (const float*)d_in[1];
  const float* diss = (const float*)d_in[2];
  float* msn = (float*)d_ws;
  float* outp = (float*)d_out;
  msnorm_kernel<<<MREF, 256, 0, stream>>>(ms, msn);
  consonance_kernel<<<BATCH, 256, 0, stream>>>(Y, ms, diss, msn, outp);
}